// Round 12
// baseline (1150.933 us; speedup 1.0000x reference)
//
#include <hip/hip_runtime.h>

#define NB 2
#define CIN 3
#define HH 512
#define WW 512
#define C2 64
#define HM 504   // mode-pool output size

typedef float v2f  __attribute__((ext_vector_type(2)));
typedef float v2fu __attribute__((ext_vector_type(2), aligned(4)));

// ---------------- K2: quantize (inline) + mode pool 11x11 -> u8 [2,3,504,504] ----------------
// v1 form (measured-good; R9's sliding-window v2 regressed ~70us: latency-bound)
__global__ __launch_bounds__(256) void k_mode(const float* __restrict__ x,
                                              unsigned char* __restrict__ hmode) {
  __shared__ unsigned char tile[26 * 26];
  int bc  = blockIdx.z;
  int ty0 = blockIdx.y * 16, tx0 = blockIdx.x * 16;
  const float* src = x + (size_t)bc * HH * WW;
  for (int i = threadIdx.x; i < 26 * 26; i += 256) {
    int r = i / 26, cl = i % 26;
    int Y = ty0 + r, X = tx0 + cl;      // padded coords (pad=1)
    unsigned char v = 0;
    if (Y >= 1 && Y <= HH && X >= 1 && X <= WW) {
      float val = src[(Y - 1) * WW + (X - 1)];
      float q = rintf((val * 255.0f) / 16.0f);   // matches jnp.round(x*255/16), RNE
      q = fminf(fmaxf(q, 0.0f), 16.0f);
      v = (unsigned char)(int)q;
    }
    tile[i] = v;
  }
  __syncthreads();
  int ty = threadIdx.x >> 4, tx = threadIdx.x & 15;
  int oy = ty0 + ty, ox = tx0 + tx;
  if (oy >= HM || ox >= HM) return;
  unsigned long long w0 = 0, w1 = 0, w2 = 0;
  for (int dy = 0; dy < 11; dy++) {
    #pragma unroll
    for (int dx = 0; dx < 11; dx++) {
      int b = tile[(ty + dy) * 26 + tx + dx];
      unsigned long long inc = 1ull << ((b & 7) * 8);
      if (b < 8) w0 += inc;
      else if (b < 16) w1 += inc;
      else w2 += inc;
    }
  }
  int best = -1, bestb = 0;
  #pragma unroll
  for (int b = 0; b < 17; b++) {
    int cnt;
    if (b < 8)       cnt = (int)((w0 >> (b * 8)) & 0xff);
    else if (b < 16) cnt = (int)((w1 >> ((b - 8) * 8)) & 0xff);
    else             cnt = (int)(w2 & 0xff);
    if (cnt > best) { best = cnt; bestb = b; }   // strict > keeps lowest bin on tie
  }
  hmode[bc * HM * HM + oy * HM + ox] = (unsigned char)bestb;
}

// ---------------- K3: fused conv1+maxleaky + grouped conv2 + minleaky + downgrade ----------------
__global__ __launch_bounds__(256) void k_prepare(const unsigned char* __restrict__ hmode,
                                                 const float* __restrict__ w1,
                                                 const float* __restrict__ b1,
                                                 const float* __restrict__ w2,
                                                 const float* __restrict__ b2,
                                                 const float* __restrict__ down_k,
                                                 const float* __restrict__ down_b,
                                                 float* __restrict__ d1) {
  int bc = blockIdx.y;
  int b  = bc >> 6;
  int c  = bc & 63;
  int pix = blockIdx.x * 256 + threadIdx.x;
  if (pix >= 168 * 168) return;
  int oy = pix / 168, ox = pix % 168;
  int c0 = (c >> 1) << 1;
  float w1a0 = w1[c0 * 3], w1a1 = w1[c0 * 3 + 1], w1a2 = w1[c0 * 3 + 2], b1a = b1[c0];
  float w1b0 = w1[(c0 + 1) * 3], w1b1 = w1[(c0 + 1) * 3 + 1], w1b2 = w1[(c0 + 1) * 3 + 2], b1b = b1[c0 + 1];
  float w2a = w2[c * 2], w2b = w2[c * 2 + 1], b2c = b2[c];
  float kb = *down_b;
  const unsigned char* h0p = hmode + (b * 3 + 0) * HM * HM;
  const unsigned char* h1p = hmode + (b * 3 + 1) * HM * HM;
  const unsigned char* h2p = hmode + (b * 3 + 2) * HM * HM;
  float acc = 0.0f;
  #pragma unroll
  for (int ky = 0; ky < 3; ky++) {
    int y = 3 * oy - 1 + ky;
    if (y < 0 || y >= HM) continue;
    #pragma unroll
    for (int kx = 0; kx < 3; kx++) {
      int xx = 3 * ox - 1 + kx;
      if (xx < 0 || xx >= HM) continue;
      int o = y * HM + xx;
      float hh0 = h0p[o] * (1.0f / 16.0f);
      float hh1 = h1p[o] * (1.0f / 16.0f);
      float hh2 = h2p[o] * (1.0f / 16.0f);
      float a0 = w1a0 * hh0 + w1a1 * hh1 + w1a2 * hh2 + b1a;
      float a1 = w1b0 * hh0 + w1b1 * hh1 + w1b2 * hh2 + b1b;
      a0 = (a0 <= 0.1f) ? a0 : 0.1f + 0.01f * (a0 - 0.1f);
      a1 = (a1 <= 0.1f) ? a1 : 0.1f + 0.01f * (a1 - 0.1f);
      float v = w2a * a0 + w2b * a1 + b2c;
      v = (v >= 0.1f) ? v : 0.1f + 0.01f * (v - 0.1f);
      acc += down_k[ky * 3 + kx] * v;
    }
  }
  float r = acc + kb;
  r = (r >= 0.0f) ? r : 0.01f * r;
  d1[bc * 168 * 168 + pix] = r;
}

// ---------------- K4: fused downgrade chain d1->d2->d3->d4->d5, one launch ----------------
__global__ __launch_bounds__(256) void k_down_all(const float* __restrict__ d1g,
                                                  float* __restrict__ d2g,
                                                  float* __restrict__ d3g,
                                                  float* __restrict__ d4g,
                                                  float* __restrict__ d5g,
                                                  const float* __restrict__ down_k,
                                                  const float* __restrict__ down_b) {
  __shared__ float s2[56 * 56];
  __shared__ float s3[19 * 19];
  __shared__ float s4[7 * 7];
  int bc = blockIdx.x;
  int tid = threadIdx.x;
  float kb = *down_b;
  float k[9];
  #pragma unroll
  for (int i = 0; i < 9; i++)
    k[i] = __int_as_float(__builtin_amdgcn_readfirstlane(__float_as_int(down_k[i])));

  const float* p1 = d1g + (size_t)bc * 168 * 168;
  for (int pix = tid; pix < 56 * 56; pix += 256) {
    int oy = pix / 56, ox = pix % 56;
    float acc = 0.0f;
    #pragma unroll
    for (int ky = 0; ky < 3; ky++) {
      int y = 3 * oy - 1 + ky;
      if (y < 0 || y >= 168) continue;
      #pragma unroll
      for (int kx = 0; kx < 3; kx++) {
        int xx = 3 * ox - 1 + kx;
        if (xx < 0 || xx >= 168) continue;
        acc += k[ky * 3 + kx] * p1[y * 168 + xx];
      }
    }
    float r = acc + kb;
    r = (r >= 0.0f) ? r : 0.01f * r;
    s2[pix] = r;
    d2g[(size_t)bc * 56 * 56 + pix] = r;
  }
  __syncthreads();
  for (int pix = tid; pix < 19 * 19; pix += 256) {
    int oy = pix / 19, ox = pix % 19;
    float acc = 0.0f;
    #pragma unroll
    for (int ky = 0; ky < 3; ky++) {
      int y = 3 * oy - 1 + ky;
      if (y < 0 || y >= 56) continue;
      #pragma unroll
      for (int kx = 0; kx < 3; kx++) {
        int xx = 3 * ox - 1 + kx;
        if (xx < 0 || xx >= 56) continue;
        acc += k[ky * 3 + kx] * s2[y * 56 + xx];
      }
    }
    float r = acc + kb;
    r = (r >= 0.0f) ? r : 0.01f * r;
    s3[pix] = r;
    d3g[(size_t)bc * 19 * 19 + pix] = r;
  }
  __syncthreads();
  for (int pix = tid; pix < 7 * 7; pix += 256) {
    int oy = pix / 7, ox = pix % 7;
    float acc = 0.0f;
    #pragma unroll
    for (int ky = 0; ky < 3; ky++) {
      int y = 3 * oy - 1 + ky;
      if (y < 0 || y >= 19) continue;
      #pragma unroll
      for (int kx = 0; kx < 3; kx++) {
        int xx = 3 * ox - 1 + kx;
        if (xx < 0 || xx >= 19) continue;
        acc += k[ky * 3 + kx] * s3[y * 19 + xx];
      }
    }
    float r = acc + kb;
    r = (r >= 0.0f) ? r : 0.01f * r;
    s4[pix] = r;
    d4g[(size_t)bc * 7 * 7 + pix] = r;
  }
  __syncthreads();
  for (int pix = tid; pix < 3 * 3; pix += 256) {
    int oy = pix / 3, ox = pix % 3;
    float acc = 0.0f;
    #pragma unroll
    for (int ky = 0; ky < 3; ky++) {
      int y = 3 * oy - 1 + ky;
      if (y < 0 || y >= 7) continue;
      #pragma unroll
      for (int kx = 0; kx < 3; kx++) {
        int xx = 3 * ox - 1 + kx;
        if (xx < 0 || xx >= 7) continue;
        acc += k[ky * 3 + kx] * s4[y * 7 + xx];
      }
    }
    float r = acc + kb;
    r = (r >= 0.0f) ? r : 0.01f * r;
    d5g[(size_t)bc * 3 * 3 + pix] = r;
  }
}

// ---------------- K_lut: packed bilinear LUT {asfloat(y0), w} per level/coord ----------------
__global__ __launch_bounds__(256) void k_lut(float2* __restrict__ lutpk) {
  int idx = blockIdx.x * 256 + threadIdx.x;   // 5*512
  if (idx >= 5 * 512) return;
  int lvl = idx >> 9, Y = idx & 511;
  const int Ls[5] = {168, 56, 19, 7, 3};
  int L = Ls[lvl];
  float f = (Y + 0.5f) * ((float)L / 512.0f) - 0.5f;
  f = fminf(fmaxf(f, 0.0f), (float)(L - 1));
  int y0 = (int)f;
  float w = f - (float)y0;
  lutpk[idx] = make_float2(__int_as_float(y0), w);
}

// ---------------- K5: composite 5-level resize+conv+BN+leaky+sum, v4 ----------------
// Loop-swap union-of-rows form (conflicts 5.5e6). This round: launch_bounds
// (256,4)->(256,6): VGPR=64 (8-wave cap per m69) and LDS=24KB (6 blocks/CU)
// both allow 6 blocks; the old bound self-capped at 4 blocks (Occupancy 41%,
// VALUBusy 59% -> issue-limited with idle slots).
#define XI(cc) ((cc) + ((((cc) >> 5)) << 2))
#define XSTR 148
__global__ __launch_bounds__(256, 6) void k_score(const float* __restrict__ d1,
                                                  const float* __restrict__ d2,
                                                  const float* __restrict__ d3,
                                                  const float* __restrict__ d4,
                                                  const float* __restrict__ d5,
                                                  const float2* __restrict__ lutpk,
                                                  const float* __restrict__ interp_k,
                                                  const float* __restrict__ interp_b,
                                                  const float* __restrict__ i_gamma,
                                                  const float* __restrict__ i_beta,
                                                  const float* __restrict__ i_mean,
                                                  const float* __restrict__ i_var,
                                                  float* __restrict__ score) {
  __shared__ float xrow[24 * XSTR];    // [r][XI(xx)]
  __shared__ float kap[64 * 36];       // [y][rr*8 + kx], 5 used per slot
  __shared__ int   abase[64];          // a0base(y) - r0

  int bc = blockIdx.y;
  int c  = bc & 63;
  int tile = blockIdx.x;               // 32 tiles: 8 y-tiles x 4 x-tiles
  int tyi = tile >> 2, txi = tile & 3;
  int ty0 = tyi * 64, tx0 = txi * 128;
  float K[25];
  #pragma unroll
  for (int i = 0; i < 25; i++)
    K[i] = __int_as_float(__builtin_amdgcn_readfirstlane(__float_as_int(interp_k[i])));
  float ib  = __int_as_float(__builtin_amdgcn_readfirstlane(__float_as_int(*interp_b)));
  float isc = i_gamma[c] * rsqrtf(i_var[c] + 1e-5f);
  float ibe = i_beta[c] - i_mean[c] * isc;
  int tid = threadIdx.x;
  int oyl = (tid >> 4) << 2, oxl = (tid & 15) << 3;  // 4x8 px per thread
  const int pA = XI(oxl);              // col oxl   (A; B = pA+4)
  const int pC = XI(oxl + 8);          // col oxl+8 (Cx)
  float acc[4][8];
  #pragma unroll
  for (int i = 0; i < 4; i++)
    #pragma unroll
    for (int j = 0; j < 8; j++) acc[i][j] = 0.0f;

  const float* dls[5] = {d1, d2, d3, d4, d5};
  const int Ls[5]  = {168, 56, 19, 7, 3};
  const int RLs[5] = {24, 10, 5, 3, 3};

  auto fillLevel = [&](int l) {
    int L = Ls[l], RR = RLs[l];
    const float* dp = dls[l] + bc * L * L;
    const float2* lp = lutpk + (l << 9);
    int Ylo = max(ty0 - 2, 0);
    int r0 = __float_as_int(lp[Ylo].x);
    // kappa: thread tid -> (y = tid>>2, rrel = tid&3)
    {
      int y = tid >> 2, rr = tid & 3;
      int Y = ty0 + y;
      float kv0 = 0.0f, kv1 = 0.0f, kv2 = 0.0f, kv3 = 0.0f, kv4 = 0.0f;
      int ab = -1;
      #pragma unroll
      for (int ky = 0; ky < 5; ky++) {
        int yy = Y + ky - 2;
        if (yy >= 0 && yy < 512) {
          float2 pk = lp[yy];
          int a0 = __float_as_int(pk.x);
          float wv = pk.y;
          if (ab < 0) ab = a0;           // first valid ky has the min a0 (monotone)
          float cf = 0.0f;
          if (a0 - ab == rr)     cf += 1.0f - wv;
          if (a0 + 1 - ab == rr) cf += wv;
          kv0 += cf * K[ky * 5 + 0];
          kv1 += cf * K[ky * 5 + 1];
          kv2 += cf * K[ky * 5 + 2];
          kv3 += cf * K[ky * 5 + 3];
          kv4 += cf * K[ky * 5 + 4];
        }
      }
      float* kp = &kap[y * 36 + rr * 8];
      kp[0] = kv0; kp[1] = kv1; kp[2] = kv2; kp[3] = kv3; kp[4] = kv4;
      if (rr == 0) abase[y] = ab - r0;
    }
    // xrow: x-upsample coarse rows, zero outside image columns
    for (int i = tid; i < RR * 132; i += 256) {
      int r = i / 132, xx = i - r * 132;
      int X = tx0 - 2 + xx;
      float v = 0.0f;
      if (X >= 0 && X < 512) {
        float2 pk = lp[X];
        int ix = __float_as_int(pk.x);
        float wx = pk.y;
        int gr = min(r0 + r, L - 1);
        const float* rp = dp + gr * L + ix;
        float v0 = rp[0], v1 = rp[1];    // v1 unused when wx==0 (clamp)
        v = v0 + wx * (v1 - v0);
      }
      xrow[r * XSTR + XI(xx)] = v;
    }
  };

  auto convAcc = [&](int rspan, int rlim) {
    int ab0 = abase[oyl];
    int ab1 = abase[oyl + 1];
    int ab2 = abase[oyl + 2];
    int ab3 = abase[oyl + 3];
    float t[4][8];
    #pragma unroll
    for (int i = 0; i < 4; i++)
      #pragma unroll
      for (int j = 0; j < 8; j++) t[i][j] = 0.0f;
    int gend = ab3 + rspan;              // exclusive; abase monotone so union = [ab0, gend)
    for (int g = ab0; g < gend; ++g) {
      int row = min(g, rlim);            // kappa==0 whenever clamp engages
      const float* xp = &xrow[row * XSTR];
      float4 A = *(const float4*)(xp + pA);
      float4 B = *(const float4*)(xp + pA + 4);
      float4 Cx = *(const float4*)(xp + pC);
      float wnd[12] = {A.x, A.y, A.z, A.w, B.x, B.y, B.z, B.w, Cx.x, Cx.y, Cx.z, Cx.w};
      int abv[4] = {ab0, ab1, ab2, ab3};
      #pragma unroll
      for (int i = 0; i < 4; i++) {
        int rr = g - abv[i];
        if (rr >= 0 && rr < rspan) {
          const float* kp = &kap[(oyl + i) * 36 + rr * 8];
          float4 kk = *(const float4*)kp;
          float k4v = kp[4];
          #pragma unroll
          for (int j = 0; j < 8; j++)
            t[i][j] += kk.x * wnd[j] + kk.y * wnd[j + 1] + kk.z * wnd[j + 2] +
                       kk.w * wnd[j + 3] + k4v * wnd[j + 4];
        }
      }
    }
    #pragma unroll
    for (int i = 0; i < 4; i++)
      #pragma unroll
      for (int j = 0; j < 8; j++) {
        float v = (t[i][j] + ib) * isc + ibe;
        v = (v >= 0.0f) ? v : 0.01f * v;
        acc[i][j] += v;
      }
  };

  #pragma unroll 1
  for (int l = 0; l < 5; l++) {
    if (l) __syncthreads();              // conv(l-1) done with LDS
    fillLevel(l);
    __syncthreads();
    if (l == 0) convAcc(4, RLs[0] - 1);
    else        convAcc(3, RLs[l] - 1);
  }

  float* op = score + bc * 512 * 512;
  #pragma unroll
  for (int i = 0; i < 4; i++) {
    int Y = ty0 + oyl + i;
    float* orow = op + Y * 512 + tx0 + oxl;
    *(float4*)(orow)     = make_float4(acc[i][0], acc[i][1], acc[i][2], acc[i][3]);
    *(float4*)(orow + 4) = make_float4(acc[i][4], acc[i][5], acc[i][6], acc[i][7]);
  }
}

// ---------------- K6: 3x ft vertical pipeline, v2, 4 bands (REVERTED from R11's
// 8-band split: halo re-read amplification + warm-up growth outweighed the
// concurrency gain, +18us. This is the measured-good form.) ----------------
__global__ __launch_bounds__(256, 3) void k_ft_pipe(const float* __restrict__ s_in,
                                                    float* __restrict__ s_out,
                                                    const float* __restrict__ ft_gamma,
                                                    const float* __restrict__ ft_beta,
                                                    const float* __restrict__ ft_mean,
                                                    const float* __restrict__ ft_var,
                                                    const float* __restrict__ ft_k,
                                                    const float* __restrict__ ft_b,
                                                    const float* __restrict__ emph_w) {
  __shared__ float brow1[2][524];     // col c at idx c+6; pads [0..5],[518..523] = 0
  __shared__ float brow2[2][524];
  __shared__ float brow3[2][524];

  const int bc = blockIdx.y;          // 0..127
  const int c  = bc & 63;
  const int R0 = blockIdx.x << 7;     // band start row (0,128,256,384)
  const int mstart = R0 - 15;

  const float sc  = ft_gamma[c] * rsqrtf(ft_var[c] + 1e-5f);
  const float fk = *ft_k, fb = *ft_b;
  const float Aff = sc * fk;
  const float Cc  = (ft_beta[c] - ft_mean[c] * sc) * fk + fb;
  const float w   = emph_w[c];
  const float opw = 1.0f + w;
  const float okw = w * (1.0f / 121.0f);

  const int tid = threadIdx.x;
  const int x0  = tid << 1;

  const float* sp = s_in + ((size_t)bc << 18) + x0;
  float*       op = s_out + ((size_t)bc << 18) + x0;

  // zero the horizontal pads (both buffers); ordered before first read by the
  // first in-loop barrier
  if (tid < 72) {
    int a = tid / 24, pb = (tid / 12) & 1, e = tid % 12;
    int idx = (e < 6) ? e : (512 + e);
    float* base = (a == 0) ? &brow1[pb][0] : (a == 1) ? &brow2[pb][0] : &brow3[pb][0];
    base[idx] = 0.0f;
  }

  auto ldraw = [&](int row) -> v2f {
    int rc = min(max(row, 0), 511);        // clamp keeps the access in-bounds
    return *(const v2f*)(sp + ((size_t)rc << 9));
  };

  // two 11-sums (cols x0, x0+1) from brow window [x0-6 .. x0+7]
  auto rowsum = [&](const float* b) -> v2f {
    const float* p = b + x0;               // brow idx x0 == col x0-6
    v2f w0 = *(const v2f*)(p);
    v2f w1 = *(const v2f*)(p + 2);
    v2f w2 = *(const v2f*)(p + 4);
    v2f w3 = *(const v2f*)(p + 6);
    v2f w4 = *(const v2f*)(p + 8);
    v2f w5 = *(const v2f*)(p + 10);
    v2f w6 = *(const v2f*)(p + 12);
    float smid = ((w1.x + w1.y) + (w2.x + w2.y)) +
                 ((w3.x + w3.y) + (w4.x + w4.y)) + (w5.x + w5.y);   // cols x0-4..x0+5
    v2f r;
    r.x = smid + w0.y;   // + col x0-5
    r.y = smid + w6.x;   // + col x0+6
    return r;
  };

  v2f cs1 = (v2f)0.0f, cs2 = (v2f)0.0f, cs3 = (v2f)0.0f;
  v2f out1p = (v2f)0.0f, out2p = (v2f)0.0f;   // S1/S2 rows produced last step (raw)

  v2f r2[12], r3[12];                  // register rings (compile-time indexed)
  #pragma unroll
  for (int k = 0; k < 12; k++) { r2[k] = (v2f)0.0f; r3[k] = (v2f)0.0f; }

  v2f gf  = ldraw(mstart);            // row m       (stage-1 front)
  v2f gfa = ldraw(mstart + 1);        // row m+1     (front prefetch, depth 2)
  v2f go  = ldraw(mstart - 11);       // row m-11    (stage-1 subtract, L2-hot)
  v2f gc  = ldraw(mstart - 5);        // row m-5     (stage-1 center, L2-hot)

  #pragma unroll 1
  for (int ii = 0; ii < 14; ++ii) {
    #pragma unroll
    for (int j = 0; j < 12; ++j) {
      const int i = ii * 12 + j;
      const int m = mstart + i;
      // prefetch: front 2-deep (HBM-cold), others 1-deep (L2-hot re-reads)
      v2f gf_n2 = ldraw(m + 2);
      v2f go_n  = ldraw(m - 10);
      v2f gc_n  = ldraw(m - 4);

      const int p = j & 1;

      // ---------------- W phase: advance column sums, publish C rows ----------------
      {  // stage 1: front row m
        v2f u1f = (m >= 0 && m < 512) ? (gf * Aff + Cc) : (v2f)0.0f;
        int r = m - 11;
        v2f u1o = (r >= mstart && r >= 0 && r < 512) ? (go * Aff + Cc) : (v2f)0.0f;
        cs1 += u1f - u1o;                            // cs1 = colsum at row m-5
        *(v2f*)(&brow1[p][6 + x0]) = cs1;
      }
      {  // stage 2: front row m-6 (consumes out1p = S1(m-6))
        v2f u2s = out1p * Aff + Cc;
        v2f u2or = r2[(j + 1) % 12];                 // value from 11 iters ago
        r2[j] = u2s;
        int rf = m - 6;
        v2f u2f = (rf >= 0 && rf < 512) ? u2s : (v2f)0.0f;
        int r = m - 17;
        v2f u2o = (r >= mstart - 6 && r >= 0 && r < 512) ? u2or : (v2f)0.0f;
        cs2 += u2f - u2o;                            // cs2 = colsum at row m-11
        *(v2f*)(&brow2[p][6 + x0]) = cs2;
      }
      {  // stage 3: front row m-12 (consumes out2p = S2(m-12))
        v2f u3s = out2p * Aff + Cc;
        v2f u3or = r3[(j + 1) % 12];
        r3[j] = u3s;
        int rf = m - 12;
        v2f u3f = (rf >= 0 && rf < 512) ? u3s : (v2f)0.0f;
        int r = m - 23;
        v2f u3o = (r >= mstart - 12 && r >= 0 && r < 512) ? u3or : (v2f)0.0f;
        cs3 += u3f - u3o;                            // cs3 = colsum at row m-17
        *(v2f*)(&brow3[p][6 + x0]) = cs3;
      }
      __syncthreads();                               // brow[p] published
      // ---------------- R phase: horizontal 11-sums, emit stage outputs ----------------
      {  // S1(m-5)
        int rc1 = m - 5;
        v2f u1c = (rc1 >= 0 && rc1 < 512) ? (gc * Aff + Cc) : (v2f)0.0f;
        v2f B1 = rowsum(&brow1[p][0]);
        out1p = u1c * opw - B1 * okw;
      }
      {  // S2(m-11)
        int rc2 = m - 11;
        v2f u2cr = r2[(j + 7) % 12];                 // value from 5 iters ago
        v2f u2c = (rc2 >= mstart - 6 && rc2 >= 0 && rc2 < 512) ? u2cr : (v2f)0.0f;
        v2f B2 = rowsum(&brow2[p][0]);
        out2p = u2c * opw - B2 * okw;
      }
      {  // S3(m-17) -> global
        int rc3 = m - 17;
        v2f u3cr = r3[(j + 7) % 12];
        v2f u3c = (rc3 >= mstart - 12 && rc3 >= 0 && rc3 < 512) ? u3cr : (v2f)0.0f;
        v2f B3 = rowsum(&brow3[p][0]);
        v2f o3 = u3c * opw - B3 * okw;
        if (i >= 32 && i < 160)
          *(v2f*)(op + ((size_t)(m - 17) << 9)) = o3;   // rows R0 .. R0+127
      }
      // no second barrier: next iter writes brow[p^1]; brow[p] is rewritten
      // two iters from now, ordered after this R by the next iter's barrier.
      gf = gfa; gfa = gf_n2; go = go_n; gc = gc_n;
    }
  }
}

extern "C" void kernel_launch(void* const* d_in, const int* in_sizes, int n_in,
                              void* d_out, int out_size, void* d_ws, size_t ws_size,
                              hipStream_t stream) {
  const float* x        = (const float*)d_in[0];
  const float* w1       = (const float*)d_in[1];
  const float* b1       = (const float*)d_in[2];
  const float* w2       = (const float*)d_in[3];
  const float* b2       = (const float*)d_in[4];
  const float* down_k   = (const float*)d_in[5];
  const float* down_b   = (const float*)d_in[6];
  const float* ft_gamma = (const float*)d_in[7];
  const float* ft_beta  = (const float*)d_in[8];
  const float* ft_mean  = (const float*)d_in[9];
  const float* ft_var   = (const float*)d_in[10];
  const float* ft_k     = (const float*)d_in[11];
  const float* ft_b     = (const float*)d_in[12];
  const float* emph_w   = (const float*)d_in[13];
  const float* interp_k = (const float*)d_in[14];
  const float* interp_b = (const float*)d_in[15];
  const float* i_gamma  = (const float*)d_in[16];
  const float* i_beta   = (const float*)d_in[17];
  const float* i_mean   = (const float*)d_in[18];
  const float* i_var    = (const float*)d_in[19];
  float* out = (float*)d_out;                    // [2,64,512,512]

  char* ws = (char*)d_ws;
  size_t off = 0;
  auto alloc = [&](size_t bytes) { size_t r = off; off += (bytes + 255) & ~(size_t)255; return r; };
  unsigned char* hmode = (unsigned char*)(ws + alloc((size_t)NB * CIN * HM * HM));
  float* d1 = (float*)(ws + alloc((size_t)NB * C2 * 168 * 168 * 4));
  float* d2 = (float*)(ws + alloc((size_t)NB * C2 * 56 * 56 * 4));
  float* d3 = (float*)(ws + alloc((size_t)NB * C2 * 19 * 19 * 4));
  float* d4 = (float*)(ws + alloc((size_t)NB * C2 * 7 * 7 * 4));
  float* d5 = (float*)(ws + alloc((size_t)NB * C2 * 3 * 3 * 4));
  float* s0 = (float*)(ws + alloc((size_t)NB * C2 * 512 * 512 * 4));  // pre-ft score
  float2* lutpk = (float2*)(ws + alloc((size_t)5 * 512 * 8));

  k_mode<<<dim3(32, 32, NB * CIN), 256, 0, stream>>>(x, hmode);
  k_lut<<<10, 256, 0, stream>>>(lutpk);
  k_prepare<<<dim3((168 * 168 + 255) / 256, NB * C2), 256, 0, stream>>>(
      hmode, w1, b1, w2, b2, down_k, down_b, d1);
  k_down_all<<<dim3(NB * C2), 256, 0, stream>>>(d1, d2, d3, d4, d5, down_k, down_b);
  k_score<<<dim3(32, NB * C2), 256, 0, stream>>>(d1, d2, d3, d4, d5, lutpk,
                                                 interp_k, interp_b,
                                                 i_gamma, i_beta, i_mean, i_var, s0);
  k_ft_pipe<<<dim3(4, NB * C2), 256, 0, stream>>>(s0, out, ft_gamma, ft_beta, ft_mean,
                                                  ft_var, ft_k, ft_b, emph_w);
}

// Round 13
// 545.842 us; speedup vs baseline: 2.1085x; 2.1085x over previous
//
#include <hip/hip_runtime.h>

#define NB 2
#define CIN 3
#define HH 512
#define WW 512
#define C2 64
#define HM 504   // mode-pool output size

typedef float v2f  __attribute__((ext_vector_type(2)));
typedef float v2fu __attribute__((ext_vector_type(2), aligned(4)));

// ---------------- K2: quantize (inline) + mode pool 11x11 -> u8 [2,3,504,504] ----------------
// v1 form (measured-good; R9's sliding-window v2 regressed ~70us: latency-bound)
__global__ __launch_bounds__(256) void k_mode(const float* __restrict__ x,
                                              unsigned char* __restrict__ hmode) {
  __shared__ unsigned char tile[26 * 26];
  int bc  = blockIdx.z;
  int ty0 = blockIdx.y * 16, tx0 = blockIdx.x * 16;
  const float* src = x + (size_t)bc * HH * WW;
  for (int i = threadIdx.x; i < 26 * 26; i += 256) {
    int r = i / 26, cl = i % 26;
    int Y = ty0 + r, X = tx0 + cl;      // padded coords (pad=1)
    unsigned char v = 0;
    if (Y >= 1 && Y <= HH && X >= 1 && X <= WW) {
      float val = src[(Y - 1) * WW + (X - 1)];
      float q = rintf((val * 255.0f) / 16.0f);   // matches jnp.round(x*255/16), RNE
      q = fminf(fmaxf(q, 0.0f), 16.0f);
      v = (unsigned char)(int)q;
    }
    tile[i] = v;
  }
  __syncthreads();
  int ty = threadIdx.x >> 4, tx = threadIdx.x & 15;
  int oy = ty0 + ty, ox = tx0 + tx;
  if (oy >= HM || ox >= HM) return;
  unsigned long long w0 = 0, w1 = 0, w2 = 0;
  for (int dy = 0; dy < 11; dy++) {
    #pragma unroll
    for (int dx = 0; dx < 11; dx++) {
      int b = tile[(ty + dy) * 26 + tx + dx];
      unsigned long long inc = 1ull << ((b & 7) * 8);
      if (b < 8) w0 += inc;
      else if (b < 16) w1 += inc;
      else w2 += inc;
    }
  }
  int best = -1, bestb = 0;
  #pragma unroll
  for (int b = 0; b < 17; b++) {
    int cnt;
    if (b < 8)       cnt = (int)((w0 >> (b * 8)) & 0xff);
    else if (b < 16) cnt = (int)((w1 >> ((b - 8) * 8)) & 0xff);
    else             cnt = (int)(w2 & 0xff);
    if (cnt > best) { best = cnt; bestb = b; }   // strict > keeps lowest bin on tie
  }
  hmode[bc * HM * HM + oy * HM + ox] = (unsigned char)bestb;
}

// ---------------- K3: fused conv1+maxleaky + grouped conv2 + minleaky + downgrade ----------------
__global__ __launch_bounds__(256) void k_prepare(const unsigned char* __restrict__ hmode,
                                                 const float* __restrict__ w1,
                                                 const float* __restrict__ b1,
                                                 const float* __restrict__ w2,
                                                 const float* __restrict__ b2,
                                                 const float* __restrict__ down_k,
                                                 const float* __restrict__ down_b,
                                                 float* __restrict__ d1) {
  int bc = blockIdx.y;
  int b  = bc >> 6;
  int c  = bc & 63;
  int pix = blockIdx.x * 256 + threadIdx.x;
  if (pix >= 168 * 168) return;
  int oy = pix / 168, ox = pix % 168;
  int c0 = (c >> 1) << 1;
  float w1a0 = w1[c0 * 3], w1a1 = w1[c0 * 3 + 1], w1a2 = w1[c0 * 3 + 2], b1a = b1[c0];
  float w1b0 = w1[(c0 + 1) * 3], w1b1 = w1[(c0 + 1) * 3 + 1], w1b2 = w1[(c0 + 1) * 3 + 2], b1b = b1[c0 + 1];
  float w2a = w2[c * 2], w2b = w2[c * 2 + 1], b2c = b2[c];
  float kb = *down_b;
  const unsigned char* h0p = hmode + (b * 3 + 0) * HM * HM;
  const unsigned char* h1p = hmode + (b * 3 + 1) * HM * HM;
  const unsigned char* h2p = hmode + (b * 3 + 2) * HM * HM;
  float acc = 0.0f;
  #pragma unroll
  for (int ky = 0; ky < 3; ky++) {
    int y = 3 * oy - 1 + ky;
    if (y < 0 || y >= HM) continue;
    #pragma unroll
    for (int kx = 0; kx < 3; kx++) {
      int xx = 3 * ox - 1 + kx;
      if (xx < 0 || xx >= HM) continue;
      int o = y * HM + xx;
      float hh0 = h0p[o] * (1.0f / 16.0f);
      float hh1 = h1p[o] * (1.0f / 16.0f);
      float hh2 = h2p[o] * (1.0f / 16.0f);
      float a0 = w1a0 * hh0 + w1a1 * hh1 + w1a2 * hh2 + b1a;
      float a1 = w1b0 * hh0 + w1b1 * hh1 + w1b2 * hh2 + b1b;
      a0 = (a0 <= 0.1f) ? a0 : 0.1f + 0.01f * (a0 - 0.1f);
      a1 = (a1 <= 0.1f) ? a1 : 0.1f + 0.01f * (a1 - 0.1f);
      float v = w2a * a0 + w2b * a1 + b2c;
      v = (v >= 0.1f) ? v : 0.1f + 0.01f * (v - 0.1f);
      acc += down_k[ky * 3 + kx] * v;
    }
  }
  float r = acc + kb;
  r = (r >= 0.0f) ? r : 0.01f * r;
  d1[bc * 168 * 168 + pix] = r;
}

// ---------------- K4: fused downgrade chain d1->d2->d3->d4->d5, one launch ----------------
__global__ __launch_bounds__(256) void k_down_all(const float* __restrict__ d1g,
                                                  float* __restrict__ d2g,
                                                  float* __restrict__ d3g,
                                                  float* __restrict__ d4g,
                                                  float* __restrict__ d5g,
                                                  const float* __restrict__ down_k,
                                                  const float* __restrict__ down_b) {
  __shared__ float s2[56 * 56];
  __shared__ float s3[19 * 19];
  __shared__ float s4[7 * 7];
  int bc = blockIdx.x;
  int tid = threadIdx.x;
  float kb = *down_b;
  float k[9];
  #pragma unroll
  for (int i = 0; i < 9; i++)
    k[i] = __int_as_float(__builtin_amdgcn_readfirstlane(__float_as_int(down_k[i])));

  const float* p1 = d1g + (size_t)bc * 168 * 168;
  for (int pix = tid; pix < 56 * 56; pix += 256) {
    int oy = pix / 56, ox = pix % 56;
    float acc = 0.0f;
    #pragma unroll
    for (int ky = 0; ky < 3; ky++) {
      int y = 3 * oy - 1 + ky;
      if (y < 0 || y >= 168) continue;
      #pragma unroll
      for (int kx = 0; kx < 3; kx++) {
        int xx = 3 * ox - 1 + kx;
        if (xx < 0 || xx >= 168) continue;
        acc += k[ky * 3 + kx] * p1[y * 168 + xx];
      }
    }
    float r = acc + kb;
    r = (r >= 0.0f) ? r : 0.01f * r;
    s2[pix] = r;
    d2g[(size_t)bc * 56 * 56 + pix] = r;
  }
  __syncthreads();
  for (int pix = tid; pix < 19 * 19; pix += 256) {
    int oy = pix / 19, ox = pix % 19;
    float acc = 0.0f;
    #pragma unroll
    for (int ky = 0; ky < 3; ky++) {
      int y = 3 * oy - 1 + ky;
      if (y < 0 || y >= 56) continue;
      #pragma unroll
      for (int kx = 0; kx < 3; kx++) {
        int xx = 3 * ox - 1 + kx;
        if (xx < 0 || xx >= 56) continue;
        acc += k[ky * 3 + kx] * s2[y * 56 + xx];
      }
    }
    float r = acc + kb;
    r = (r >= 0.0f) ? r : 0.01f * r;
    s3[pix] = r;
    d3g[(size_t)bc * 19 * 19 + pix] = r;
  }
  __syncthreads();
  for (int pix = tid; pix < 7 * 7; pix += 256) {
    int oy = pix / 7, ox = pix % 7;
    float acc = 0.0f;
    #pragma unroll
    for (int ky = 0; ky < 3; ky++) {
      int y = 3 * oy - 1 + ky;
      if (y < 0 || y >= 19) continue;
      #pragma unroll
      for (int kx = 0; kx < 3; kx++) {
        int xx = 3 * ox - 1 + kx;
        if (xx < 0 || xx >= 19) continue;
        acc += k[ky * 3 + kx] * s3[y * 19 + xx];
      }
    }
    float r = acc + kb;
    r = (r >= 0.0f) ? r : 0.01f * r;
    s4[pix] = r;
    d4g[(size_t)bc * 7 * 7 + pix] = r;
  }
  __syncthreads();
  for (int pix = tid; pix < 3 * 3; pix += 256) {
    int oy = pix / 3, ox = pix % 3;
    float acc = 0.0f;
    #pragma unroll
    for (int ky = 0; ky < 3; ky++) {
      int y = 3 * oy - 1 + ky;
      if (y < 0 || y >= 7) continue;
      #pragma unroll
      for (int kx = 0; kx < 3; kx++) {
        int xx = 3 * ox - 1 + kx;
        if (xx < 0 || xx >= 7) continue;
        acc += k[ky * 3 + kx] * s4[y * 7 + xx];
      }
    }
    float r = acc + kb;
    r = (r >= 0.0f) ? r : 0.01f * r;
    d5g[(size_t)bc * 3 * 3 + pix] = r;
  }
}

// ---------------- K_lut: packed bilinear LUT {asfloat(y0), w} per level/coord ----------------
__global__ __launch_bounds__(256) void k_lut(float2* __restrict__ lutpk) {
  int idx = blockIdx.x * 256 + threadIdx.x;   // 5*512
  if (idx >= 5 * 512) return;
  int lvl = idx >> 9, Y = idx & 511;
  const int Ls[5] = {168, 56, 19, 7, 3};
  int L = Ls[lvl];
  float f = (Y + 0.5f) * ((float)L / 512.0f) - 0.5f;
  f = fminf(fmaxf(f, 0.0f), (float)(L - 1));
  int y0 = (int)f;
  float w = f - (float)y0;
  lutpk[idx] = make_float2(__int_as_float(y0), w);
}

// ---------------- K5: composite 5-level resize+conv+BN+leaky+sum, v4 ----------------
// Loop-swap union-of-rows form (conflicts 5.5e6). launch_bounds REVERTED to
// (256,4): R12's (256,6) forced VGPR 64->40, spilling t/acc/window regs to
// scratch (FETCH 22MB->1.02GB, WRITE 154MB->2.45GB, 194->800us). The 2nd
// launch-bounds arg CONSTRAINS the allocator; this kernel needs ~64 VGPR.
#define XI(cc) ((cc) + ((((cc) >> 5)) << 2))
#define XSTR 148
__global__ __launch_bounds__(256, 4) void k_score(const float* __restrict__ d1,
                                                  const float* __restrict__ d2,
                                                  const float* __restrict__ d3,
                                                  const float* __restrict__ d4,
                                                  const float* __restrict__ d5,
                                                  const float2* __restrict__ lutpk,
                                                  const float* __restrict__ interp_k,
                                                  const float* __restrict__ interp_b,
                                                  const float* __restrict__ i_gamma,
                                                  const float* __restrict__ i_beta,
                                                  const float* __restrict__ i_mean,
                                                  const float* __restrict__ i_var,
                                                  float* __restrict__ score) {
  __shared__ float xrow[24 * XSTR];    // [r][XI(xx)]
  __shared__ float kap[64 * 36];       // [y][rr*8 + kx], 5 used per slot
  __shared__ int   abase[64];          // a0base(y) - r0

  int bc = blockIdx.y;
  int c  = bc & 63;
  int tile = blockIdx.x;               // 32 tiles: 8 y-tiles x 4 x-tiles
  int tyi = tile >> 2, txi = tile & 3;
  int ty0 = tyi * 64, tx0 = txi * 128;
  float K[25];
  #pragma unroll
  for (int i = 0; i < 25; i++)
    K[i] = __int_as_float(__builtin_amdgcn_readfirstlane(__float_as_int(interp_k[i])));
  float ib  = __int_as_float(__builtin_amdgcn_readfirstlane(__float_as_int(*interp_b)));
  float isc = i_gamma[c] * rsqrtf(i_var[c] + 1e-5f);
  float ibe = i_beta[c] - i_mean[c] * isc;
  int tid = threadIdx.x;
  int oyl = (tid >> 4) << 2, oxl = (tid & 15) << 3;  // 4x8 px per thread
  const int pA = XI(oxl);              // col oxl   (A; B = pA+4)
  const int pC = XI(oxl + 8);          // col oxl+8 (Cx)
  float acc[4][8];
  #pragma unroll
  for (int i = 0; i < 4; i++)
    #pragma unroll
    for (int j = 0; j < 8; j++) acc[i][j] = 0.0f;

  const float* dls[5] = {d1, d2, d3, d4, d5};
  const int Ls[5]  = {168, 56, 19, 7, 3};
  const int RLs[5] = {24, 10, 5, 3, 3};

  auto fillLevel = [&](int l) {
    int L = Ls[l], RR = RLs[l];
    const float* dp = dls[l] + bc * L * L;
    const float2* lp = lutpk + (l << 9);
    int Ylo = max(ty0 - 2, 0);
    int r0 = __float_as_int(lp[Ylo].x);
    // kappa: thread tid -> (y = tid>>2, rrel = tid&3)
    {
      int y = tid >> 2, rr = tid & 3;
      int Y = ty0 + y;
      float kv0 = 0.0f, kv1 = 0.0f, kv2 = 0.0f, kv3 = 0.0f, kv4 = 0.0f;
      int ab = -1;
      #pragma unroll
      for (int ky = 0; ky < 5; ky++) {
        int yy = Y + ky - 2;
        if (yy >= 0 && yy < 512) {
          float2 pk = lp[yy];
          int a0 = __float_as_int(pk.x);
          float wv = pk.y;
          if (ab < 0) ab = a0;           // first valid ky has the min a0 (monotone)
          float cf = 0.0f;
          if (a0 - ab == rr)     cf += 1.0f - wv;
          if (a0 + 1 - ab == rr) cf += wv;
          kv0 += cf * K[ky * 5 + 0];
          kv1 += cf * K[ky * 5 + 1];
          kv2 += cf * K[ky * 5 + 2];
          kv3 += cf * K[ky * 5 + 3];
          kv4 += cf * K[ky * 5 + 4];
        }
      }
      float* kp = &kap[y * 36 + rr * 8];
      kp[0] = kv0; kp[1] = kv1; kp[2] = kv2; kp[3] = kv3; kp[4] = kv4;
      if (rr == 0) abase[y] = ab - r0;
    }
    // xrow: x-upsample coarse rows, zero outside image columns
    for (int i = tid; i < RR * 132; i += 256) {
      int r = i / 132, xx = i - r * 132;
      int X = tx0 - 2 + xx;
      float v = 0.0f;
      if (X >= 0 && X < 512) {
        float2 pk = lp[X];
        int ix = __float_as_int(pk.x);
        float wx = pk.y;
        int gr = min(r0 + r, L - 1);
        const float* rp = dp + gr * L + ix;
        float v0 = rp[0], v1 = rp[1];    // v1 unused when wx==0 (clamp)
        v = v0 + wx * (v1 - v0);
      }
      xrow[r * XSTR + XI(xx)] = v;
    }
  };

  auto convAcc = [&](int rspan, int rlim) {
    int ab0 = abase[oyl];
    int ab1 = abase[oyl + 1];
    int ab2 = abase[oyl + 2];
    int ab3 = abase[oyl + 3];
    float t[4][8];
    #pragma unroll
    for (int i = 0; i < 4; i++)
      #pragma unroll
      for (int j = 0; j < 8; j++) t[i][j] = 0.0f;
    int gend = ab3 + rspan;              // exclusive; abase monotone so union = [ab0, gend)
    for (int g = ab0; g < gend; ++g) {
      int row = min(g, rlim);            // kappa==0 whenever clamp engages
      const float* xp = &xrow[row * XSTR];
      float4 A = *(const float4*)(xp + pA);
      float4 B = *(const float4*)(xp + pA + 4);
      float4 Cx = *(const float4*)(xp + pC);
      float wnd[12] = {A.x, A.y, A.z, A.w, B.x, B.y, B.z, B.w, Cx.x, Cx.y, Cx.z, Cx.w};
      int abv[4] = {ab0, ab1, ab2, ab3};
      #pragma unroll
      for (int i = 0; i < 4; i++) {
        int rr = g - abv[i];
        if (rr >= 0 && rr < rspan) {
          const float* kp = &kap[(oyl + i) * 36 + rr * 8];
          float4 kk = *(const float4*)kp;
          float k4v = kp[4];
          #pragma unroll
          for (int j = 0; j < 8; j++)
            t[i][j] += kk.x * wnd[j] + kk.y * wnd[j + 1] + kk.z * wnd[j + 2] +
                       kk.w * wnd[j + 3] + k4v * wnd[j + 4];
        }
      }
    }
    #pragma unroll
    for (int i = 0; i < 4; i++)
      #pragma unroll
      for (int j = 0; j < 8; j++) {
        float v = (t[i][j] + ib) * isc + ibe;
        v = (v >= 0.0f) ? v : 0.01f * v;
        acc[i][j] += v;
      }
  };

  #pragma unroll 1
  for (int l = 0; l < 5; l++) {
    if (l) __syncthreads();              // conv(l-1) done with LDS
    fillLevel(l);
    __syncthreads();
    if (l == 0) convAcc(4, RLs[0] - 1);
    else        convAcc(3, RLs[l] - 1);
  }

  float* op = score + bc * 512 * 512;
  #pragma unroll
  for (int i = 0; i < 4; i++) {
    int Y = ty0 + oyl + i;
    float* orow = op + Y * 512 + tx0 + oxl;
    *(float4*)(orow)     = make_float4(acc[i][0], acc[i][1], acc[i][2], acc[i][3]);
    *(float4*)(orow + 4) = make_float4(acc[i][4], acc[i][5], acc[i][6], acc[i][7]);
  }
}

// ---------------- K6: 3x ft vertical pipeline, v2, 4 bands (measured-good form) ----------------
__global__ __launch_bounds__(256, 3) void k_ft_pipe(const float* __restrict__ s_in,
                                                    float* __restrict__ s_out,
                                                    const float* __restrict__ ft_gamma,
                                                    const float* __restrict__ ft_beta,
                                                    const float* __restrict__ ft_mean,
                                                    const float* __restrict__ ft_var,
                                                    const float* __restrict__ ft_k,
                                                    const float* __restrict__ ft_b,
                                                    const float* __restrict__ emph_w) {
  __shared__ float brow1[2][524];     // col c at idx c+6; pads [0..5],[518..523] = 0
  __shared__ float brow2[2][524];
  __shared__ float brow3[2][524];

  const int bc = blockIdx.y;          // 0..127
  const int c  = bc & 63;
  const int R0 = blockIdx.x << 7;     // band start row (0,128,256,384)
  const int mstart = R0 - 15;

  const float sc  = ft_gamma[c] * rsqrtf(ft_var[c] + 1e-5f);
  const float fk = *ft_k, fb = *ft_b;
  const float Aff = sc * fk;
  const float Cc  = (ft_beta[c] - ft_mean[c] * sc) * fk + fb;
  const float w   = emph_w[c];
  const float opw = 1.0f + w;
  const float okw = w * (1.0f / 121.0f);

  const int tid = threadIdx.x;
  const int x0  = tid << 1;

  const float* sp = s_in + ((size_t)bc << 18) + x0;
  float*       op = s_out + ((size_t)bc << 18) + x0;

  // zero the horizontal pads (both buffers); ordered before first read by the
  // first in-loop barrier
  if (tid < 72) {
    int a = tid / 24, pb = (tid / 12) & 1, e = tid % 12;
    int idx = (e < 6) ? e : (512 + e);
    float* base = (a == 0) ? &brow1[pb][0] : (a == 1) ? &brow2[pb][0] : &brow3[pb][0];
    base[idx] = 0.0f;
  }

  auto ldraw = [&](int row) -> v2f {
    int rc = min(max(row, 0), 511);        // clamp keeps the access in-bounds
    return *(const v2f*)(sp + ((size_t)rc << 9));
  };

  // two 11-sums (cols x0, x0+1) from brow window [x0-6 .. x0+7]
  auto rowsum = [&](const float* b) -> v2f {
    const float* p = b + x0;               // brow idx x0 == col x0-6
    v2f w0 = *(const v2f*)(p);
    v2f w1 = *(const v2f*)(p + 2);
    v2f w2 = *(const v2f*)(p + 4);
    v2f w3 = *(const v2f*)(p + 6);
    v2f w4 = *(const v2f*)(p + 8);
    v2f w5 = *(const v2f*)(p + 10);
    v2f w6 = *(const v2f*)(p + 12);
    float smid = ((w1.x + w1.y) + (w2.x + w2.y)) +
                 ((w3.x + w3.y) + (w4.x + w4.y)) + (w5.x + w5.y);   // cols x0-4..x0+5
    v2f r;
    r.x = smid + w0.y;   // + col x0-5
    r.y = smid + w6.x;   // + col x0+6
    return r;
  };

  v2f cs1 = (v2f)0.0f, cs2 = (v2f)0.0f, cs3 = (v2f)0.0f;
  v2f out1p = (v2f)0.0f, out2p = (v2f)0.0f;   // S1/S2 rows produced last step (raw)

  v2f r2[12], r3[12];                  // register rings (compile-time indexed)
  #pragma unroll
  for (int k = 0; k < 12; k++) { r2[k] = (v2f)0.0f; r3[k] = (v2f)0.0f; }

  v2f gf  = ldraw(mstart);            // row m       (stage-1 front)
  v2f gfa = ldraw(mstart + 1);        // row m+1     (front prefetch, depth 2)
  v2f go  = ldraw(mstart - 11);       // row m-11    (stage-1 subtract, L2-hot)
  v2f gc  = ldraw(mstart - 5);        // row m-5     (stage-1 center, L2-hot)

  #pragma unroll 1
  for (int ii = 0; ii < 14; ++ii) {
    #pragma unroll
    for (int j = 0; j < 12; ++j) {
      const int i = ii * 12 + j;
      const int m = mstart + i;
      // prefetch: front 2-deep (HBM-cold), others 1-deep (L2-hot re-reads)
      v2f gf_n2 = ldraw(m + 2);
      v2f go_n  = ldraw(m - 10);
      v2f gc_n  = ldraw(m - 4);

      const int p = j & 1;

      // ---------------- W phase: advance column sums, publish C rows ----------------
      {  // stage 1: front row m
        v2f u1f = (m >= 0 && m < 512) ? (gf * Aff + Cc) : (v2f)0.0f;
        int r = m - 11;
        v2f u1o = (r >= mstart && r >= 0 && r < 512) ? (go * Aff + Cc) : (v2f)0.0f;
        cs1 += u1f - u1o;                            // cs1 = colsum at row m-5
        *(v2f*)(&brow1[p][6 + x0]) = cs1;
      }
      {  // stage 2: front row m-6 (consumes out1p = S1(m-6))
        v2f u2s = out1p * Aff + Cc;
        v2f u2or = r2[(j + 1) % 12];                 // value from 11 iters ago
        r2[j] = u2s;
        int rf = m - 6;
        v2f u2f = (rf >= 0 && rf < 512) ? u2s : (v2f)0.0f;
        int r = m - 17;
        v2f u2o = (r >= mstart - 6 && r >= 0 && r < 512) ? u2or : (v2f)0.0f;
        cs2 += u2f - u2o;                            // cs2 = colsum at row m-11
        *(v2f*)(&brow2[p][6 + x0]) = cs2;
      }
      {  // stage 3: front row m-12 (consumes out2p = S2(m-12))
        v2f u3s = out2p * Aff + Cc;
        v2f u3or = r3[(j + 1) % 12];
        r3[j] = u3s;
        int rf = m - 12;
        v2f u3f = (rf >= 0 && rf < 512) ? u3s : (v2f)0.0f;
        int r = m - 23;
        v2f u3o = (r >= mstart - 12 && r >= 0 && r < 512) ? u3or : (v2f)0.0f;
        cs3 += u3f - u3o;                            // cs3 = colsum at row m-17
        *(v2f*)(&brow3[p][6 + x0]) = cs3;
      }
      __syncthreads();                               // brow[p] published
      // ---------------- R phase: horizontal 11-sums, emit stage outputs ----------------
      {  // S1(m-5)
        int rc1 = m - 5;
        v2f u1c = (rc1 >= 0 && rc1 < 512) ? (gc * Aff + Cc) : (v2f)0.0f;
        v2f B1 = rowsum(&brow1[p][0]);
        out1p = u1c * opw - B1 * okw;
      }
      {  // S2(m-11)
        int rc2 = m - 11;
        v2f u2cr = r2[(j + 7) % 12];                 // value from 5 iters ago
        v2f u2c = (rc2 >= mstart - 6 && rc2 >= 0 && rc2 < 512) ? u2cr : (v2f)0.0f;
        v2f B2 = rowsum(&brow2[p][0]);
        out2p = u2c * opw - B2 * okw;
      }
      {  // S3(m-17) -> global
        int rc3 = m - 17;
        v2f u3cr = r3[(j + 7) % 12];
        v2f u3c = (rc3 >= mstart - 12 && rc3 >= 0 && rc3 < 512) ? u3cr : (v2f)0.0f;
        v2f B3 = rowsum(&brow3[p][0]);
        v2f o3 = u3c * opw - B3 * okw;
        if (i >= 32 && i < 160)
          *(v2f*)(op + ((size_t)(m - 17) << 9)) = o3;   // rows R0 .. R0+127
      }
      // no second barrier: next iter writes brow[p^1]; brow[p] is rewritten
      // two iters from now, ordered after this R by the next iter's barrier.
      gf = gfa; gfa = gf_n2; go = go_n; gc = gc_n;
    }
  }
}

extern "C" void kernel_launch(void* const* d_in, const int* in_sizes, int n_in,
                              void* d_out, int out_size, void* d_ws, size_t ws_size,
                              hipStream_t stream) {
  const float* x        = (const float*)d_in[0];
  const float* w1       = (const float*)d_in[1];
  const float* b1       = (const float*)d_in[2];
  const float* w2       = (const float*)d_in[3];
  const float* b2       = (const float*)d_in[4];
  const float* down_k   = (const float*)d_in[5];
  const float* down_b   = (const float*)d_in[6];
  const float* ft_gamma = (const float*)d_in[7];
  const float* ft_beta  = (const float*)d_in[8];
  const float* ft_mean  = (const float*)d_in[9];
  const float* ft_var   = (const float*)d_in[10];
  const float* ft_k     = (const float*)d_in[11];
  const float* ft_b     = (const float*)d_in[12];
  const float* emph_w   = (const float*)d_in[13];
  const float* interp_k = (const float*)d_in[14];
  const float* interp_b = (const float*)d_in[15];
  const float* i_gamma  = (const float*)d_in[16];
  const float* i_beta   = (const float*)d_in[17];
  const float* i_mean   = (const float*)d_in[18];
  const float* i_var    = (const float*)d_in[19];
  float* out = (float*)d_out;                    // [2,64,512,512]

  char* ws = (char*)d_ws;
  size_t off = 0;
  auto alloc = [&](size_t bytes) { size_t r = off; off += (bytes + 255) & ~(size_t)255; return r; };
  unsigned char* hmode = (unsigned char*)(ws + alloc((size_t)NB * CIN * HM * HM));
  float* d1 = (float*)(ws + alloc((size_t)NB * C2 * 168 * 168 * 4));
  float* d2 = (float*)(ws + alloc((size_t)NB * C2 * 56 * 56 * 4));
  float* d3 = (float*)(ws + alloc((size_t)NB * C2 * 19 * 19 * 4));
  float* d4 = (float*)(ws + alloc((size_t)NB * C2 * 7 * 7 * 4));
  float* d5 = (float*)(ws + alloc((size_t)NB * C2 * 3 * 3 * 4));
  float* s0 = (float*)(ws + alloc((size_t)NB * C2 * 512 * 512 * 4));  // pre-ft score
  float2* lutpk = (float2*)(ws + alloc((size_t)5 * 512 * 8));

  k_mode<<<dim3(32, 32, NB * CIN), 256, 0, stream>>>(x, hmode);
  k_lut<<<10, 256, 0, stream>>>(lutpk);
  k_prepare<<<dim3((168 * 168 + 255) / 256, NB * C2), 256, 0, stream>>>(
      hmode, w1, b1, w2, b2, down_k, down_b, d1);
  k_down_all<<<dim3(NB * C2), 256, 0, stream>>>(d1, d2, d3, d4, d5, down_k, down_b);
  k_score<<<dim3(32, NB * C2), 256, 0, stream>>>(d1, d2, d3, d4, d5, lutpk,
                                                 interp_k, interp_b,
                                                 i_gamma, i_beta, i_mean, i_var, s0);
  k_ft_pipe<<<dim3(4, NB * C2), 256, 0, stream>>>(s0, out, ft_gamma, ft_beta, ft_mean,
                                                  ft_var, ft_k, ft_b, emph_w);
}